// Round 23
// baseline (466.298 us; speedup 1.0000x reference)
//
#include <hip/hip_runtime.h>
#include <hip/hip_bf16.h>
#include <hip/hip_fp16.h>
#include <math.h>

// ---------------------------------------------------------------------------
// GATGNN forward. fp32 math; edge streams fp16, ALL CSR-ordered (~140 MB ws).
//   CSR build (hierarchical scan); k_fill emits pos[i] (coalesced) and
//   srcp/dstp (scattered posted writes).
//   h = x@Wn + bn (coalesced, fp32 core);
//   ea-embed: MFMA kernel (K=41 padded), float4 staging, rows scattered to
//   ea[pos[e]] (posted).
//   per layer:
//     P = h@Wtop (fp16)  [layers 1,2: BN+softplus fused into staging]
//     k_efused (MFMA 16x16x32 f16): EARLY P prefetch (covers gather latency
//            under staging+barrier); M = ea@Wbot; acc->disjoint LDS (1 barrier
//            only); epilogue: ti=sp(Pd+M), tj=sp(Ps+M); M<-tj; a1=sp(att dot);
//            a1 stats -> 64-way banked atomics
//     aggregate: sequential CSR walk; banked col stats
//   final h = sp(BN(aggn)); comp attention (LDS-tiled, ILP) + pool + fc
// Lessons pinned:
//  - NEVER pass min-waves to __launch_bounds__ (r6/r7 GB-scale spills).
//  - r9: full-unroll reg tiles -> VGPR 144, occupancy collapse.
//  - r11/r15: same-address L2 atomic ~22ns serialized; keep <=128/address.
//  - r15: no serial cross-lane chains in hot loops.
//  - r16: single-block scan = 92us Amdahl tail -> hierarchical.
//  - r17/r18/r20: 64-col GEMMs belong on the matrix pipe; randomness rides
//    the WRITE side (posted), never the read side.
//  - r21/r22: staging starves MFMA if scalar; vectorize. Prefetch gathers
//    BEFORE the staging barrier; alias-free acc buffer saves a barrier.
// ---------------------------------------------------------------------------

typedef unsigned short ushortt;
typedef _Float16 f16x8 __attribute__((ext_vector_type(8)));
typedef float f32x4 __attribute__((ext_vector_type(4)));

__device__ __forceinline__ float sp_f(float x) {
  return x > 20.0f ? x : __logf(1.0f + __expf(x));
}
__device__ __forceinline__ float h2f(ushortt u) {
  union { ushortt u; __half h; } c; c.u = u;
  return __half2float(c.h);
}
__device__ __forceinline__ ushortt f2h(float f) {
  union { __half h; ushortt u; } c; c.h = __float2half(f);
  return c.u;
}
__device__ __forceinline__ float4 h4_to_f4(ushort4 u) {
  return make_float4(h2f(u.x), h2f(u.y), h2f(u.z), h2f(u.w));
}

// per-layer stats block layout (floats), stride SLOTS:
//   [0..63] a1 sum banks  [64..127] a1 sumsq banks
//   [128 .. 128+16*128)   col-stats cs, 16 banks x (64 sum + 64 sumsq)
#define SLOTS 2304

// ---------- generic register-tiled GEMM (node-side, fp32 LDS) ---------------
template<int K, int ACT, int BIAS, int FUSE_BN, typename IT, typename OT>
__global__ __launch_bounds__(256) void k_gemm_rt(
    const IT* __restrict__ in, const float* __restrict__ W,
    const float* __restrict__ b, OT* __restrict__ out, int R,
    const float* __restrict__ csbn, float invN)
{
  constexpr int KP = (K + 3) / 4 * 4;
  constexpr int LS0 = KP + 4;
  constexpr int LS = ((4 * LS0) % 32 == 0) ? LS0 + 4 : LS0;
  __shared__ __align__(16) float ins[64 * LS];
  __shared__ __align__(16) float Ws[KP * 64];
  __shared__ float bnm[64], bns[64];

  const int tx = threadIdx.x;
  const int b0 = blockIdx.x * 64;

  if (FUSE_BN) {
    if (tx < 64) {
      float mn = 0.f, sq = 0.f;
      #pragma unroll
      for (int bk = 0; bk < 16; ++bk) {
        mn += csbn[bk * 128 + tx];
        sq += csbn[bk * 128 + 64 + tx];
      }
      mn *= invN; sq *= invN;
      bnm[tx] = mn;
      bns[tx] = rsqrtf(sq - mn * mn + 1e-5f);
    }
    __syncthreads();
  }

  for (int i = tx; i < KP * 64; i += 256) {
    const int k = i >> 6;
    Ws[i] = (k < K) ? W[i] : 0.0f;
  }
  for (int i = tx; i < 64 * (KP / 4); i += 256) {
    const int row = i / (KP / 4);
    const int k4 = i % (KP / 4);
    long r = b0 + row; if (r >= R) r = R - 1;   // clamp: values unused
    float4 v;
    if (K % 4 == 0) {
      v = *(const float4*)&((const float*)in)[r * (long)K + k4 * 4];
    } else {
      float t[4];
      #pragma unroll
      for (int j = 0; j < 4; ++j) {
        const int k = k4 * 4 + j;
        t[j] = (k < K) ? ((const float*)in)[r * (long)K + k] : 0.0f;
      }
      v = make_float4(t[0], t[1], t[2], t[3]);
    }
    if (FUSE_BN) {
      float* vv = (float*)&v;
      #pragma unroll
      for (int j = 0; j < 4; ++j) {
        const int c = k4 * 4 + j;
        vv[j] = sp_f((vv[j] - bnm[c]) * bns[c]);
      }
    }
    *(float4*)&ins[row * LS + k4 * 4] = v;
  }
  __syncthreads();

  const int lr0 = ((tx >> 6) << 4) + (((tx >> 4) & 3) << 2);
  const int c0 = (tx & 15) << 2;
  float acc[4][4];
  #pragma unroll
  for (int i = 0; i < 4; ++i)
    #pragma unroll
    for (int j = 0; j < 4; ++j) acc[i][j] = 0.0f;

  #pragma unroll 4
  for (int k4 = 0; k4 < KP / 4; ++k4) {
    float4 w[4], a[4];
    #pragma unroll
    for (int kk = 0; kk < 4; ++kk)
      w[kk] = *(const float4*)&Ws[(k4 * 4 + kk) * 64 + c0];
    #pragma unroll
    for (int ri = 0; ri < 4; ++ri)
      a[ri] = *(const float4*)&ins[(lr0 + ri) * LS + k4 * 4];
    #pragma unroll
    for (int ri = 0; ri < 4; ++ri) {
      const float* av = (const float*)&a[ri];
      #pragma unroll
      for (int kk = 0; kk < 4; ++kk) {
        acc[ri][0] = fmaf(av[kk], w[kk].x, acc[ri][0]);
        acc[ri][1] = fmaf(av[kk], w[kk].y, acc[ri][1]);
        acc[ri][2] = fmaf(av[kk], w[kk].z, acc[ri][2]);
        acc[ri][3] = fmaf(av[kk], w[kk].w, acc[ri][3]);
      }
    }
  }

  float4 bias = make_float4(0.f, 0.f, 0.f, 0.f);
  if (BIAS) bias = *(const float4*)&b[c0];
  #pragma unroll
  for (int ri = 0; ri < 4; ++ri) {
    const long r = b0 + lr0 + ri;
    if (r >= R) continue;
    float4 v;
    v.x = acc[ri][0] + bias.x; v.y = acc[ri][1] + bias.y;
    v.z = acc[ri][2] + bias.z; v.w = acc[ri][3] + bias.w;
    if (ACT == 1) {
      v.x = v.x >= 0.f ? v.x : 0.2f * v.x;  v.y = v.y >= 0.f ? v.y : 0.2f * v.y;
      v.z = v.z >= 0.f ? v.z : 0.2f * v.z;  v.w = v.w >= 0.f ? v.w : 0.2f * v.w;
    }
    if (sizeof(OT) == 4) {
      *(float4*)&out[r * 64 + c0] = v;
    } else {
      ushort4 u;
      u.x = f2h(v.x); u.y = f2h(v.y); u.z = f2h(v.z); u.w = f2h(v.w);
      *(ushort4*)&out[r * 64 + c0] = u;
    }
  }
}

// ---------- W pre-pack into MFMA B-fragment order ---------------------------
__global__ __launch_bounds__(512) void k_packW(
    const float* __restrict__ convW, uint4* __restrict__ WBg)
{
  const int l3 = blockIdx.x;
  const float* W = convW + (size_t)l3 * 128 * 64 + 64 * 64;   // Wbot
  const int idx = threadIdx.x;
  const int kstep = idx >> 8;
  const int rem = idx & 255;
  const int ncol = rem >> 6;
  const int l = rem & 63;
  const int kbase = kstep * 32 + (l >> 4) * 8;
  const int n = ncol * 16 + (l & 15);
  ushortt tmp[8];
  #pragma unroll
  for (int j = 0; j < 8; ++j) tmp[j] = f2h(W[(kbase + j) * 64 + n]);
  WBg[l3 * 512 + idx] = *(uint4*)tmp;
}

// embeW (41x64): zero-pad k>=41.
__global__ __launch_bounds__(512) void k_packWe(
    const float* __restrict__ We, uint4* __restrict__ WBe)
{
  const int idx = threadIdx.x;
  const int kstep = idx >> 8;
  const int rem = idx & 255;
  const int ncol = rem >> 6;
  const int l = rem & 63;
  const int kbase = kstep * 32 + (l >> 4) * 8;
  const int n = ncol * 16 + (l & 15);
  ushortt tmp[8];
  #pragma unroll
  for (int j = 0; j < 8; ++j) {
    const int k = kbase + j;
    tmp[j] = (k < 41) ? f2h(We[k * 64 + n]) : (ushortt)0;
  }
  WBe[idx] = *(uint4*)tmp;
}

// ---------- ea-embed via MFMA: ea[pos[e]] = leaky(eattr[e]@We + be) ---------
// Disjoint accs buffer (r23): only one barrier after MFMA.
__global__ __launch_bounds__(256) void k_embE(
    const float* __restrict__ eattr, const uint4* __restrict__ WBe,
    const float* __restrict__ be, ushortt* __restrict__ ea, int E,
    const int* __restrict__ pos)
{
  __shared__ __align__(16) ushortt As[64 * 56];   // 7168B
  __shared__ __align__(16) uint4 WB[512];         // 8192B
  __shared__ __align__(16) float accs[64 * 68];   // 17408B (disjoint)

  const int tx = threadIdx.x;
  const int b0 = blockIdx.x * 64;
  const int lane = tx & 63;
  const int w = tx >> 6;

  for (int i = tx; i < 448; i += 256) {
    const int row = i / 7;
    As[row * 56 + 41 + (i % 7)] = 0;
  }
  {
    const long fbase = (long)b0 * 41;
    const int rows = (E - b0 < 64) ? (E - b0) : 64;
    const int flim = rows * 41;
    for (int i = tx; i < 656; i += 256) {
      const int q0 = i * 4;
      if (q0 >= flim) continue;
      if (q0 + 3 < flim) {
        const float4 v = *(const float4*)&eattr[fbase + q0];
        #pragma unroll
        for (int j = 0; j < 4; ++j) {
          const int q = q0 + j;
          const int row = q / 41;
          const int k = q - row * 41;
          As[row * 56 + k] = f2h(((const float*)&v)[j]);
        }
      } else {
        for (int q = q0; q < flim; ++q) {
          const int row = q / 41;
          const int k = q - row * 41;
          As[row * 56 + k] = f2h(eattr[fbase + q]);
        }
      }
    }
  }
  #pragma unroll
  for (int i = tx; i < 512; i += 256) WB[i] = WBe[i];
  __syncthreads();

  f32x4 acc0 = {0.f,0.f,0.f,0.f}, acc1 = {0.f,0.f,0.f,0.f};
  f32x4 acc2 = {0.f,0.f,0.f,0.f}, acc3 = {0.f,0.f,0.f,0.f};
  const int arow = 16 * w + (lane & 15);
  #pragma unroll
  for (int kstep = 0; kstep < 2; ++kstep) {
    const int koff = kstep * 32 + (lane >> 4) * 8;
    f16x8 a;
    if (koff < 48) {
      a = __builtin_bit_cast(f16x8, *(const uint4*)&As[arow * 56 + koff]);
    } else {
      const uint4 z = {0u, 0u, 0u, 0u};
      a = __builtin_bit_cast(f16x8, z);
    }
    const int bb = kstep * 256 + lane;
    const f16x8 b0v = __builtin_bit_cast(f16x8, WB[bb]);
    const f16x8 b1v = __builtin_bit_cast(f16x8, WB[bb + 64]);
    const f16x8 b2v = __builtin_bit_cast(f16x8, WB[bb + 128]);
    const f16x8 b3v = __builtin_bit_cast(f16x8, WB[bb + 192]);
    acc0 = __builtin_amdgcn_mfma_f32_16x16x32_f16(a, b0v, acc0, 0, 0, 0);
    acc1 = __builtin_amdgcn_mfma_f32_16x16x32_f16(a, b1v, acc1, 0, 0, 0);
    acc2 = __builtin_amdgcn_mfma_f32_16x16x32_f16(a, b2v, acc2, 0, 0, 0);
    acc3 = __builtin_amdgcn_mfma_f32_16x16x32_f16(a, b3v, acc3, 0, 0, 0);
  }

  {
    const int rbase = 16 * w + (lane >> 4) * 4;
    const int cb = lane & 15;
    #pragma unroll
    for (int reg = 0; reg < 4; ++reg) {
      accs[(rbase + reg) * 68 + cb]      = acc0[reg];
      accs[(rbase + reg) * 68 + 16 + cb] = acc1[reg];
      accs[(rbase + reg) * 68 + 32 + cb] = acc2[reg];
      accs[(rbase + reg) * 68 + 48 + cb] = acc3[reg];
    }
  }
  __syncthreads();   // cross-lane visibility of accs (only barrier post-MFMA)

  const int lr0 = ((tx >> 6) << 4) + (((tx >> 4) & 3) << 2);
  const int c0 = (tx & 15) << 2;
  const float4 bias = *(const float4*)&be[c0];
  #pragma unroll
  for (int ri = 0; ri < 4; ++ri) {
    const long e = b0 + lr0 + ri;
    if (e >= E) continue;
    float4 v = *(const float4*)&accs[(lr0 + ri) * 68 + c0];
    v.x += bias.x; v.y += bias.y; v.z += bias.z; v.w += bias.w;
    v.x = v.x >= 0.f ? v.x : 0.2f * v.x;  v.y = v.y >= 0.f ? v.y : 0.2f * v.y;
    v.z = v.z >= 0.f ? v.z : 0.2f * v.z;  v.w = v.w >= 0.f ? v.w : 0.2f * v.w;
    ushort4 u;
    u.x = f2h(v.x); u.y = f2h(v.y); u.z = f2h(v.z); u.w = f2h(v.w);
    *(ushort4*)&ea[(long)pos[e] * 64 + c0] = u;   // scattered posted store
  }
}

// ---------- fused E-GEMM via MFMA -------------------------------------------
// r23: EARLY P prefetch (before staging -> staging+barrier covers latency);
// disjoint accs buffer (one barrier after MFMA instead of two).
__global__ __launch_bounds__(256) void k_efused(
    const ushortt* __restrict__ ea, const uint4* __restrict__ WBg,
    ushortt* __restrict__ out, int E, const ushortt* __restrict__ P,
    const int* __restrict__ srcp, const int* __restrict__ dstp,
    const float* __restrict__ catt, float* __restrict__ a1,
    float* __restrict__ stats)
{
  __shared__ __align__(16) ushortt As[64 * 72];   // 9216B
  __shared__ __align__(16) uint4 WB[512];         // 8192B
  __shared__ __align__(16) float accs[64 * 68];   // 17408B (disjoint)
  __shared__ float atts[128];
  __shared__ float ssum[4], ssq[4];

  const int tx = threadIdx.x;
  const int b0 = blockIdx.x * 64;
  const int lane = tx & 63;
  const int w = tx >> 6;

  // EARLY prefetch: P gathers issued before any staging traffic.
  const int lr0 = ((tx >> 6) << 4) + (((tx >> 4) & 3) << 2);
  const int c0 = (tx & 15) << 2;
  ushort4 pdv[4], psv[4];
  #pragma unroll
  for (int ri = 0; ri < 4; ++ri) {
    long e = b0 + lr0 + ri; if (e >= E) e = E - 1;  // clamp: values unused
    const int s = srcp[e];
    const int d = dstp[e];
    psv[ri] = *(const ushort4*)&P[(long)s * 64 + c0];
    pdv[ri] = *(const ushort4*)&P[(long)d * 64 + c0];
  }

  if (tx < 128) atts[tx] = catt[tx];
  #pragma unroll
  for (int i = tx; i < 64 * 8; i += 256) {
    const int row = i >> 3;
    const int k8 = i & 7;
    long r = b0 + row; if (r >= E) r = E - 1;
    *(uint4*)&As[row * 72 + k8 * 8] = *(const uint4*)&ea[r * (long)64 + k8 * 8];
  }
  #pragma unroll
  for (int i = tx; i < 512; i += 256) WB[i] = WBg[i];
  __syncthreads();

  f32x4 acc0 = {0.f,0.f,0.f,0.f}, acc1 = {0.f,0.f,0.f,0.f};
  f32x4 acc2 = {0.f,0.f,0.f,0.f}, acc3 = {0.f,0.f,0.f,0.f};
  const int arow = 16 * w + (lane & 15);
  #pragma unroll
  for (int kstep = 0; kstep < 2; ++kstep) {
    const f16x8 a = __builtin_bit_cast(f16x8,
        *(const uint4*)&As[arow * 72 + kstep * 32 + (lane >> 4) * 8]);
    const int bb = kstep * 256 + lane;
    const f16x8 b0v = __builtin_bit_cast(f16x8, WB[bb]);
    const f16x8 b1v = __builtin_bit_cast(f16x8, WB[bb + 64]);
    const f16x8 b2v = __builtin_bit_cast(f16x8, WB[bb + 128]);
    const f16x8 b3v = __builtin_bit_cast(f16x8, WB[bb + 192]);
    acc0 = __builtin_amdgcn_mfma_f32_16x16x32_f16(a, b0v, acc0, 0, 0, 0);
    acc1 = __builtin_amdgcn_mfma_f32_16x16x32_f16(a, b1v, acc1, 0, 0, 0);
    acc2 = __builtin_amdgcn_mfma_f32_16x16x32_f16(a, b2v, acc2, 0, 0, 0);
    acc3 = __builtin_amdgcn_mfma_f32_16x16x32_f16(a, b3v, acc3, 0, 0, 0);
  }

  // acc -> disjoint LDS (C layout col=lane&15, row=(lane>>4)*4+reg, m89)
  {
    const int rbase = 16 * w + (lane >> 4) * 4;
    const int cb = lane & 15;
    #pragma unroll
    for (int reg = 0; reg < 4; ++reg) {
      accs[(rbase + reg) * 68 + cb]      = acc0[reg];
      accs[(rbase + reg) * 68 + 16 + cb] = acc1[reg];
      accs[(rbase + reg) * 68 + 32 + cb] = acc2[reg];
      accs[(rbase + reg) * 68 + 48 + cb] = acc3[reg];
    }
  }
  __syncthreads();   // cross-lane visibility (only barrier post-MFMA)

  float s1 = 0.f, s2 = 0.f;
  #pragma unroll
  for (int ri = 0; ri < 4; ++ri) {
    const long e = b0 + lr0 + ri;
    float part = 0.0f;
    if (e < E) {
      const float4 Pd = h4_to_f4(pdv[ri]);
      const float4 Ps = h4_to_f4(psv[ri]);
      const float4 m = *(const float4*)&accs[(lr0 + ri) * 68 + c0];
      float tj[4];
      const float ti0 = sp_f(Pd.x + m.x);
      const float ti1 = sp_f(Pd.y + m.y);
      const float ti2 = sp_f(Pd.z + m.z);
      const float ti3 = sp_f(Pd.w + m.w);
      tj[0] = sp_f(Ps.x + m.x);
      tj[1] = sp_f(Ps.y + m.y);
      tj[2] = sp_f(Ps.z + m.z);
      tj[3] = sp_f(Ps.w + m.w);
      ushort4 u;
      u.x = f2h(tj[0]); u.y = f2h(tj[1]); u.z = f2h(tj[2]); u.w = f2h(tj[3]);
      *(ushort4*)&out[e * 64 + c0] = u;
      part = ti0 * atts[c0] + ti1 * atts[c0 + 1] + ti2 * atts[c0 + 2] + ti3 * atts[c0 + 3]
           + tj[0] * atts[64 + c0] + tj[1] * atts[64 + c0 + 1]
           + tj[2] * atts[64 + c0 + 2] + tj[3] * atts[64 + c0 + 3];
    }
    #pragma unroll
    for (int off = 8; off; off >>= 1) part += __shfl_xor(part, off);
    if ((tx & 15) == 0 && e < E) {
      const float v = sp_f(part);
      a1[e] = v;
      s1 += v; s2 += v * v;
    }
  }
  s1 += __shfl_xor(s1, 16); s2 += __shfl_xor(s2, 16);
  s1 += __shfl_xor(s1, 32); s2 += __shfl_xor(s2, 32);
  if ((tx & 63) == 0) { ssum[tx >> 6] = s1; ssq[tx >> 6] = s2; }
  __syncthreads();
  if (tx == 0) {
    const int bk = blockIdx.x & 63;   // 64-way banked (r11/r15 lesson)
    atomicAdd(&stats[bk], ssum[0] + ssum[1] + ssum[2] + ssum[3]);
    atomicAdd(&stats[64 + bk], ssq[0] + ssq[1] + ssq[2] + ssq[3]);
  }
}

// ---------- CSR build (once per launch) -------------------------------------
__global__ __launch_bounds__(256) void k_count(
    const int* __restrict__ dst, int* __restrict__ counts, int E)
{
  for (int i = blockIdx.x * 256 + threadIdx.x; i < E; i += gridDim.x * 256)
    atomicAdd(&counts[dst[i]], 1);
}

__global__ __launch_bounds__(256) void k_scan1(
    const int* __restrict__ counts, int* __restrict__ offs,
    int* __restrict__ bsum, int N)
{
  __shared__ int sm[256];
  const int t = threadIdx.x;
  const int idx = blockIdx.x * 256 + t;
  const int v = (idx < N) ? counts[idx] : 0;
  sm[t] = v;
  __syncthreads();
  for (int off = 1; off < 256; off <<= 1) {
    const int u = (t >= off) ? sm[t - off] : 0;
    __syncthreads();
    sm[t] += u;
    __syncthreads();
  }
  if (idx < N) offs[idx] = sm[t] - v;
  if (t == 255) bsum[blockIdx.x] = sm[255];
}

__global__ __launch_bounds__(1024) void k_scan2(int* __restrict__ bsum, int SB)
{
  __shared__ int sm[1024];
  const int t = threadIdx.x;
  const int v = (t < SB) ? bsum[t] : 0;
  sm[t] = v;
  __syncthreads();
  for (int off = 1; off < 1024; off <<= 1) {
    const int u = (t >= off) ? sm[t - off] : 0;
    __syncthreads();
    sm[t] += u;
    __syncthreads();
  }
  if (t < SB) bsum[t] = sm[t] - v;
}

__global__ __launch_bounds__(256) void k_scan3(
    int* __restrict__ offs, const int* __restrict__ bsum, int N, int E)
{
  const int idx = blockIdx.x * 256 + threadIdx.x;
  if (idx < N) offs[idx] += bsum[blockIdx.x];
  if (idx == 0) offs[N] = E;
}

__global__ __launch_bounds__(256) void k_fill(
    const int* __restrict__ src, const int* __restrict__ dst,
    const int* __restrict__ offs, int* __restrict__ cursors,
    int* __restrict__ pos, int* __restrict__ srcp, int* __restrict__ dstp,
    int E)
{
  for (int i = blockIdx.x * 256 + threadIdx.x; i < E; i += gridDim.x * 256) {
    const int d = dst[i];
    const int p = offs[d] + atomicAdd(&cursors[d], 1);
    pos[i] = p;
    srcp[p] = src[i];
    dstp[p] = d;
  }
}

// ---------- aggregate: sequential CSR reads, banked stats -------------------
__global__ __launch_bounds__(256) void k_aggregate(
    const int* __restrict__ offs, const float* __restrict__ a1p,
    const ushortt* __restrict__ Mp, const float* __restrict__ stats,
    float invE, float* __restrict__ aggn, float* __restrict__ cs, int N)
{
  __shared__ float sm_mean, sm_scl;
  const int tx = threadIdx.x;
  if (tx < 64) {
    float s1 = stats[tx];
    float s2 = stats[64 + tx];
    #pragma unroll
    for (int off = 32; off; off >>= 1) {
      s1 += __shfl_xor(s1, off);
      s2 += __shfl_xor(s2, off);
    }
    if (tx == 0) {
      const float mean = s1 * invE;
      sm_mean = mean;
      sm_scl = rsqrtf(s2 * invE - mean * mean + 1e-5f);
    }
  }
  __syncthreads();
  const float mean = sm_mean;
  const float scl = sm_scl;

  const int t = tx & 63;
  const int wid = tx >> 6;
  float s = 0.f, s2 = 0.f;
  const long step = (long)gridDim.x * 4;
  for (long n = (long)blockIdx.x * 4 + wid; n < N; n += step) {
    const int o0 = offs[n];
    const int o1 = offs[n + 1];
    float av = 0.f, sew = 0.f;
    #pragma unroll 4
    for (int i = o0; i < o1; ++i) {
      const float w = __expf(sp_f((a1p[i] - mean) * scl));
      av = fmaf(h2f(Mp[(long)i * 64 + t]), w, av);
      sew += w;
    }
    const float v = (o1 > o0) ? av / sew : 0.0f;
    aggn[n * 64 + t] = v;
    s += v; s2 += v * v;
  }
  __shared__ float b1[256], b2[256];
  b1[tx] = s; b2[tx] = s2;
  __syncthreads();
  if (tx < 64) {
    const int bank = (blockIdx.x & 15) * 128;
    atomicAdd(&cs[bank + t], b1[t] + b1[64 + t] + b1[128 + t] + b1[192 + t]);
    atomicAdd(&cs[bank + 64 + t], b2[t] + b2[64 + t] + b2[128 + t] + b2[192 + t]);
  }
}

__global__ __launch_bounds__(256) void k_hnew(
    const float* __restrict__ aggn, const float* __restrict__ cs,
    float invN, float* __restrict__ h, int N)
{
  const int c = threadIdx.x & 63;
  const int r = threadIdx.x >> 6;
  float mn = 0.f, sq = 0.f;
  #pragma unroll
  for (int bk = 0; bk < 16; ++bk) {
    mn += cs[bk * 128 + c];
    sq += cs[bk * 128 + 64 + c];
  }
  mn *= invN; sq *= invN;
  const float scl = rsqrtf(sq - mn * mn + 1e-5f);
  for (long n = (long)blockIdx.x * 4 + r; n < N; n += (long)gridDim.x * 4)
    h[n * 64 + c] = sp_f((aggn[n * 64 + c] - mn) * scl);
}

// composition attention: per block 64-node tile, LDS-staged q + Wc, 8-way ILP
#define QSS 170
__global__ __launch_bounds__(256) void k_comp(
    const float* __restrict__ h, const float* __restrict__ gf,
    const int* __restrict__ batch, const float* __restrict__ Wc,
    const float* __restrict__ bc, const float* __restrict__ aw,
    const float* __restrict__ ab, float* __restrict__ aN, int N)
{
  __shared__ __align__(16) float qs[64 * QSS];
  __shared__ __align__(16) float Wcs[167 * 32];
  __shared__ float aws[32], bcs[32];
  const int tx = threadIdx.x;
  const int b0 = blockIdx.x * 64;
  for (int i = tx; i < 167 * 32; i += 256) Wcs[i] = Wc[i];
  if (tx < 32) { aws[tx] = aw[tx]; bcs[tx] = bc[tx]; }
  for (int i = tx; i < 64 * 16; i += 256) {
    const int n = i >> 4;
    const int c4 = (i & 15) << 2;
    long r = b0 + n; if (r >= N) r = N - 1;
    *(float4*)&qs[n * QSS + c4] = *(const float4*)&h[r * 64 + c4];
  }
  for (int i = tx; i < 64 * 103; i += 256) {
    const int n = i / 103;
    const int c = i % 103;
    long r = b0 + n; if (r >= N) r = N - 1;
    qs[n * QSS + 64 + c] = gf[(long)batch[r] * 103 + c];
  }
  __syncthreads();

  const int n = tx >> 2;
  const int colg = (tx & 3) << 3;
  float acc[8];
  #pragma unroll
  for (int j = 0; j < 8; ++j) acc[j] = 0.f;
  #pragma unroll 2
  for (int k = 0; k < 167; ++k) {
    const float q = qs[n * QSS + k];
    const float4 w0 = *(const float4*)&Wcs[k * 32 + colg];
    const float4 w1 = *(const float4*)&Wcs[k * 32 + colg + 4];
    acc[0] = fmaf(q, w0.x, acc[0]);
    acc[1] = fmaf(q, w0.y, acc[1]);
    acc[2] = fmaf(q, w0.z, acc[2]);
    acc[3] = fmaf(q, w0.w, acc[3]);
    acc[4] = fmaf(q, w1.x, acc[4]);
    acc[5] = fmaf(q, w1.y, acc[5]);
    acc[6] = fmaf(q, w1.z, acc[6]);
    acc[7] = fmaf(q, w1.w, acc[7]);
  }
  float val = 0.f;
  #pragma unroll
  for (int j = 0; j < 8; ++j)
    val += sp_f(acc[j] + bcs[colg + j]) * aws[colg + j];
  val += __shfl_xor(val, 1);
  val += __shfl_xor(val, 2);
  const long r = b0 + n;
  if ((tx & 3) == 0 && r < N) aN[r] = val + ab[0];
}

__global__ __launch_bounds__(64) void k_pool(
    const float* __restrict__ h, const float* __restrict__ aN,
    const int* __restrict__ batch, const float* __restrict__ fcW,
    const float* __restrict__ fcb, float* __restrict__ out, int N, int G)
{
  const int g = blockIdx.x;
  const int t = threadIdx.x;
  int lo = 0, hi = N;
  while (lo < hi) { int mid = (lo + hi) >> 1; if (batch[mid] < g) lo = mid + 1; else hi = mid; }
  const int s = lo;
  hi = N;
  while (lo < hi) { int mid = (lo + hi) >> 1; if (batch[mid] < g + 1) lo = mid + 1; else hi = mid; }
  const int e2 = lo;
  if (s >= e2) { if (t == 0) out[g] = fcb[0]; return; }
  float mx = -1e30f;
  for (int i = s + t; i < e2; i += 64) mx = fmaxf(mx, aN[i]);
  #pragma unroll
  for (int off = 32; off; off >>= 1) mx = fmaxf(mx, __shfl_xor(mx, off));
  float se = 0.f;
  for (int i = s + t; i < e2; i += 64) se += __expf(aN[i] - mx);
  #pragma unroll
  for (int off = 32; off; off >>= 1) se += __shfl_xor(se, off);
  float acc = 0.f;
  for (int n = s; n < e2; ++n) {
    const float w = __expf(aN[n] - mx);
    acc = fmaf(h[(long)n * 64 + t], w, acc);
  }
  float part = (acc / se) * fcW[t];
  #pragma unroll
  for (int off = 32; off; off >>= 1) part += __shfl_xor(part, off);
  if (t == 0) out[g] = part + fcb[0];
}

extern "C" void kernel_launch(void* const* d_in, const int* in_sizes, int n_in,
                              void* d_out, int out_size, void* d_ws, size_t ws_size,
                              hipStream_t stream)
{
  const float* x     = (const float*)d_in[0];
  const int*   eidx  = (const int*)  d_in[1];
  const float* eattr = (const float*)d_in[2];
  const int*   batch = (const int*)  d_in[3];
  const float* gfeat = (const float*)d_in[4];
  const float* embnW = (const float*)d_in[5];
  const float* embnb = (const float*)d_in[6];
  const float* embeW = (const float*)d_in[7];
  const float* embeb = (const float*)d_in[8];
  const float* convW = (const float*)d_in[9];
  const float* convA = (const float*)d_in[10];
  // d_in[11] = conv_bias: cancels exactly in training-mode BatchNorm
  const float* compW = (const float*)d_in[12];
  const float* compb = (const float*)d_in[13];
  const float* attW  = (const float*)d_in[14];
  const float* attb  = (const float*)d_in[15];
  const float* fcW   = (const float*)d_in[16];
  const float* fcb   = (const float*)d_in[17];
  float* out = (float*)d_out;

  const int N = in_sizes[0] / 92;
  const int E = in_sizes[1] / 2;
  const int G = in_sizes[4] / 103;
  const float invN = 1.0f / (float)N;
  const float invE = 1.0f / (float)E;

  // workspace (~140 MB)
  char* pw = (char*)d_ws;
  float* h     = (float*)pw;  pw += (size_t)N * 64 * 4;
  float* aggn  = (float*)pw;  pw += (size_t)N * 64 * 4;
  float* aE    = (float*)pw;  pw += (size_t)E * 4;        // a1 (CSR-ordered)
  float* statsB = (float*)pw; pw += 3 * SLOTS * 4;
  float* aN    = (float*)pw;  pw += (size_t)N * 4;
  int* counts  = (int*)pw;    pw += (size_t)N * 4;
  int* cursors = (int*)pw;    pw += (size_t)N * 4;
  int* offs    = (int*)pw;    pw += ((size_t)N + 1) * 4;
  int* bsum    = (int*)pw;    pw += 1024 * 4;
  int* pos     = (int*)pw;    pw += (size_t)E * 4;
  int* srcp    = (int*)pw;    pw += (size_t)E * 4;
  int* dstp    = (int*)pw;    pw += (size_t)E * 4;
  pw = (char*)(((size_t)pw + 63) & ~(size_t)63);
  uint4* WBg   = (uint4*)pw;   pw += 3 * 512 * 16;        // conv B frags
  uint4* WBe   = (uint4*)pw;   pw += 512 * 16;            // embed B frags
  ushortt* Pp  = (ushortt*)pw; pw += (size_t)N * 64 * 2;  // P fp16
  ushortt* ea  = (ushortt*)pw; pw += (size_t)E * 64 * 2;  // fp16, CSR-ordered
  ushortt* M   = (ushortt*)pw;                            // fp16 tj, CSR-ordered

  const int gE64 = (E + 63) / 64;
  const int gN64 = (N + 63) / 64;
  const int SB = (N + 255) / 256;

  hipMemsetAsync(counts, 0, 2 * (size_t)N * sizeof(int), stream);
  hipMemsetAsync(statsB, 0, 3 * SLOTS * sizeof(float), stream);
  k_count<<<2048, 256, 0, stream>>>(eidx + E, counts, E);
  k_scan1<<<SB, 256, 0, stream>>>(counts, offs, bsum, N);
  k_scan2<<<1, 1024, 0, stream>>>(bsum, SB);
  k_scan3<<<SB, 256, 0, stream>>>(offs, bsum, N, E);
  k_fill<<<2048, 256, 0, stream>>>(eidx, eidx + E, offs, cursors,
                                   pos, srcp, dstp, E);
  k_packW<<<3, 512, 0, stream>>>(convW, WBg);
  k_packWe<<<1, 512, 0, stream>>>(embeW, WBe);

  k_gemm_rt<92, 0, 1, 0, float, float><<<gN64, 256, 0, stream>>>(
      x, embnW, embnb, h, N, nullptr, 0.f);
  // ea-embed on the matrix pipe; output rows scattered to CSR slots (posted)
  k_embE<<<gE64, 256, 0, stream>>>(eattr, WBe, embeb, ea, E, pos);

  for (int l = 0; l < 3; ++l) {
    const float* Al = convA + (size_t)l * 128;
    float* statsL = statsB + (size_t)l * SLOTS;
    const float* Wl = convW + (size_t)l * 128 * 64;
    if (l == 0) {
      k_gemm_rt<64, 0, 0, 0, float, ushortt><<<gN64, 256, 0, stream>>>(
          h, Wl, nullptr, Pp, N, nullptr, 0.f);
    } else {
      k_gemm_rt<64, 0, 0, 1, float, ushortt><<<gN64, 256, 0, stream>>>(
          aggn, Wl, nullptr, Pp, N,
          statsB + (size_t)(l - 1) * SLOTS + 128, invN);
    }
    k_efused<<<gE64, 256, 0, stream>>>(ea, WBg + (size_t)l * 512, M, E,
                                       Pp, srcp, dstp, Al, aE, statsL);
    k_aggregate<<<2048, 256, 0, stream>>>(offs, aE, M, statsL,
                                          invE, aggn, statsL + 128, N);
  }

  k_hnew<<<2048, 256, 0, stream>>>(aggn, statsB + 2 * SLOTS + 128, invN, h, N);
  k_comp<<<gN64, 256, 0, stream>>>(h, gfeat, batch, compW, compb, attW, attb, aN, N);
  k_pool<<<G, 64, 0, stream>>>(h, aN, batch, fcW, fcb, out, N, G);

  (void)n_in; (void)out_size; (void)ws_size;
}

// Round 24
// 447.233 us; speedup vs baseline: 1.0426x; 1.0426x over previous
//
#include <hip/hip_runtime.h>
#include <hip/hip_bf16.h>
#include <hip/hip_fp16.h>
#include <math.h>

// ---------------------------------------------------------------------------
// GATGNN forward. fp32 math; edge streams fp16, ALL CSR-ordered (~140 MB ws).
// REVERT to round-22 best (453.7us): r23's disjoint-acc buffer raised LDS
// 18.4->35.8KB, halving blocks/CU (8->4) -- occupancy IS the latency hider
// in these gather-bound kernels; never trade it for a barrier.
//   CSR build (hierarchical scan); k_fill emits pos[i] (coalesced) and
//   srcp/dstp (scattered posted writes).
//   h = x@Wn + bn (coalesced, fp32 core);
//   ea-embed: MFMA kernel (K=41 padded to 48), float4-vectorized staging,
//   output rows scattered to ea[pos[e]] (posted).
//   per layer:
//     P = h@Wtop (fp16)  [layers 1,2: BN+softplus fused into staging]
//     k_efused (MFMA 16x16x32 f16): M = ea@Wbot; acc->LDS->epilogue:
//            ti=sp(Pd+M), tj=sp(Ps+M); M<-tj; a1=sp(att dot);
//            a1 stats -> 64-way banked atomics
//     aggregate: sequential CSR walk; banked col stats
//   final h = sp(BN(aggn)); comp attention (LDS-tiled, ILP) + pool + fc
// Lessons pinned:
//  - NEVER pass min-waves to __launch_bounds__ (r6/r7 GB-scale spills).
//  - r9/r23: occupancy is the latency hider; don't trade it for VGPRs,
//    unrolls, or barrier counts.
//  - r11/r15: same-address L2 atomic ~22ns serialized; keep <=128/address.
//  - r15: no serial cross-lane chains in hot loops.
//  - r16: single-block scan = 92us Amdahl tail -> hierarchical.
//  - r17/r18/r20: 64-col GEMMs belong on the matrix pipe; randomness rides
//    the WRITE side (posted), never the read side.
//  - r21: vectorize staging or it starves the matrix pipe.
// ---------------------------------------------------------------------------

typedef unsigned short ushortt;
typedef _Float16 f16x8 __attribute__((ext_vector_type(8)));
typedef float f32x4 __attribute__((ext_vector_type(4)));

__device__ __forceinline__ float sp_f(float x) {
  return x > 20.0f ? x : __logf(1.0f + __expf(x));
}
__device__ __forceinline__ float h2f(ushortt u) {
  union { ushortt u; __half h; } c; c.u = u;
  return __half2float(c.h);
}
__device__ __forceinline__ ushortt f2h(float f) {
  union { __half h; ushortt u; } c; c.h = __float2half(f);
  return c.u;
}
__device__ __forceinline__ float4 h4_to_f4(ushort4 u) {
  return make_float4(h2f(u.x), h2f(u.y), h2f(u.z), h2f(u.w));
}

// per-layer stats block layout (floats), stride SLOTS:
//   [0..63] a1 sum banks  [64..127] a1 sumsq banks
//   [128 .. 128+16*128)   col-stats cs, 16 banks x (64 sum + 64 sumsq)
#define SLOTS 2304

// ---------- generic register-tiled GEMM (node-side, fp32 LDS) ---------------
template<int K, int ACT, int BIAS, int FUSE_BN, typename IT, typename OT>
__global__ __launch_bounds__(256) void k_gemm_rt(
    const IT* __restrict__ in, const float* __restrict__ W,
    const float* __restrict__ b, OT* __restrict__ out, int R,
    const float* __restrict__ csbn, float invN)
{
  constexpr int KP = (K + 3) / 4 * 4;
  constexpr int LS0 = KP + 4;
  constexpr int LS = ((4 * LS0) % 32 == 0) ? LS0 + 4 : LS0;
  __shared__ __align__(16) float ins[64 * LS];
  __shared__ __align__(16) float Ws[KP * 64];
  __shared__ float bnm[64], bns[64];

  const int tx = threadIdx.x;
  const int b0 = blockIdx.x * 64;

  if (FUSE_BN) {
    if (tx < 64) {
      float mn = 0.f, sq = 0.f;
      #pragma unroll
      for (int bk = 0; bk < 16; ++bk) {
        mn += csbn[bk * 128 + tx];
        sq += csbn[bk * 128 + 64 + tx];
      }
      mn *= invN; sq *= invN;
      bnm[tx] = mn;
      bns[tx] = rsqrtf(sq - mn * mn + 1e-5f);
    }
    __syncthreads();
  }

  for (int i = tx; i < KP * 64; i += 256) {
    const int k = i >> 6;
    Ws[i] = (k < K) ? W[i] : 0.0f;
  }
  for (int i = tx; i < 64 * (KP / 4); i += 256) {
    const int row = i / (KP / 4);
    const int k4 = i % (KP / 4);
    long r = b0 + row; if (r >= R) r = R - 1;   // clamp: values unused
    float4 v;
    if (K % 4 == 0) {
      v = *(const float4*)&((const float*)in)[r * (long)K + k4 * 4];
    } else {
      float t[4];
      #pragma unroll
      for (int j = 0; j < 4; ++j) {
        const int k = k4 * 4 + j;
        t[j] = (k < K) ? ((const float*)in)[r * (long)K + k] : 0.0f;
      }
      v = make_float4(t[0], t[1], t[2], t[3]);
    }
    if (FUSE_BN) {
      float* vv = (float*)&v;
      #pragma unroll
      for (int j = 0; j < 4; ++j) {
        const int c = k4 * 4 + j;
        vv[j] = sp_f((vv[j] - bnm[c]) * bns[c]);
      }
    }
    *(float4*)&ins[row * LS + k4 * 4] = v;
  }
  __syncthreads();

  const int lr0 = ((tx >> 6) << 4) + (((tx >> 4) & 3) << 2);
  const int c0 = (tx & 15) << 2;
  float acc[4][4];
  #pragma unroll
  for (int i = 0; i < 4; ++i)
    #pragma unroll
    for (int j = 0; j < 4; ++j) acc[i][j] = 0.0f;

  #pragma unroll 4
  for (int k4 = 0; k4 < KP / 4; ++k4) {
    float4 w[4], a[4];
    #pragma unroll
    for (int kk = 0; kk < 4; ++kk)
      w[kk] = *(const float4*)&Ws[(k4 * 4 + kk) * 64 + c0];
    #pragma unroll
    for (int ri = 0; ri < 4; ++ri)
      a[ri] = *(const float4*)&ins[(lr0 + ri) * LS + k4 * 4];
    #pragma unroll
    for (int ri = 0; ri < 4; ++ri) {
      const float* av = (const float*)&a[ri];
      #pragma unroll
      for (int kk = 0; kk < 4; ++kk) {
        acc[ri][0] = fmaf(av[kk], w[kk].x, acc[ri][0]);
        acc[ri][1] = fmaf(av[kk], w[kk].y, acc[ri][1]);
        acc[ri][2] = fmaf(av[kk], w[kk].z, acc[ri][2]);
        acc[ri][3] = fmaf(av[kk], w[kk].w, acc[ri][3]);
      }
    }
  }

  float4 bias = make_float4(0.f, 0.f, 0.f, 0.f);
  if (BIAS) bias = *(const float4*)&b[c0];
  #pragma unroll
  for (int ri = 0; ri < 4; ++ri) {
    const long r = b0 + lr0 + ri;
    if (r >= R) continue;
    float4 v;
    v.x = acc[ri][0] + bias.x; v.y = acc[ri][1] + bias.y;
    v.z = acc[ri][2] + bias.z; v.w = acc[ri][3] + bias.w;
    if (ACT == 1) {
      v.x = v.x >= 0.f ? v.x : 0.2f * v.x;  v.y = v.y >= 0.f ? v.y : 0.2f * v.y;
      v.z = v.z >= 0.f ? v.z : 0.2f * v.z;  v.w = v.w >= 0.f ? v.w : 0.2f * v.w;
    }
    if (sizeof(OT) == 4) {
      *(float4*)&out[r * 64 + c0] = v;
    } else {
      ushort4 u;
      u.x = f2h(v.x); u.y = f2h(v.y); u.z = f2h(v.z); u.w = f2h(v.w);
      *(ushort4*)&out[r * 64 + c0] = u;
    }
  }
}

// ---------- W pre-pack into MFMA B-fragment order ---------------------------
__global__ __launch_bounds__(512) void k_packW(
    const float* __restrict__ convW, uint4* __restrict__ WBg)
{
  const int l3 = blockIdx.x;
  const float* W = convW + (size_t)l3 * 128 * 64 + 64 * 64;   // Wbot
  const int idx = threadIdx.x;
  const int kstep = idx >> 8;
  const int rem = idx & 255;
  const int ncol = rem >> 6;
  const int l = rem & 63;
  const int kbase = kstep * 32 + (l >> 4) * 8;
  const int n = ncol * 16 + (l & 15);
  ushortt tmp[8];
  #pragma unroll
  for (int j = 0; j < 8; ++j) tmp[j] = f2h(W[(kbase + j) * 64 + n]);
  WBg[l3 * 512 + idx] = *(uint4*)tmp;
}

// embeW (41x64): zero-pad k>=41.
__global__ __launch_bounds__(512) void k_packWe(
    const float* __restrict__ We, uint4* __restrict__ WBe)
{
  const int idx = threadIdx.x;
  const int kstep = idx >> 8;
  const int rem = idx & 255;
  const int ncol = rem >> 6;
  const int l = rem & 63;
  const int kbase = kstep * 32 + (l >> 4) * 8;
  const int n = ncol * 16 + (l & 15);
  ushortt tmp[8];
  #pragma unroll
  for (int j = 0; j < 8; ++j) {
    const int k = kbase + j;
    tmp[j] = (k < 41) ? f2h(We[k * 64 + n]) : (ushortt)0;
  }
  WBe[idx] = *(uint4*)tmp;
}

// ---------- ea-embed via MFMA: ea[pos[e]] = leaky(eattr[e]@We + be) ---------
// Block 256 (4 waves), 64 edges. Staging: flat float4 reads (r21 lesson)
// + per-element LDS scatter. accs aliases As/WB (occupancy > barrier, r23).
__global__ __launch_bounds__(256) void k_embE(
    const float* __restrict__ eattr, const uint4* __restrict__ WBe,
    const float* __restrict__ be, ushortt* __restrict__ ea, int E,
    const int* __restrict__ pos)
{
  // phase1: As[64][56] halfs (7168B) + WB[512] uint4 (8192B) = 15360B
  // phase2: accs[64][68] f32 (17408B) -- same buffer
  __shared__ __align__(16) unsigned char smem[17408];
  ushortt* As   = (ushortt*)smem;          // stride 56 halfs
  uint4*   WB   = (uint4*)(smem + 7168);
  float*   accs = (float*)smem;            // stride 68 floats

  const int tx = threadIdx.x;
  const int b0 = blockIdx.x * 64;
  const int lane = tx & 63;
  const int w = tx >> 6;

  // zero the k=41..47 pad (448 halfs); tail rows (>=E) stay garbage but
  // their outputs are skipped in the epilogue.
  for (int i = tx; i < 448; i += 256) {
    const int row = i / 7;
    As[row * 56 + 41 + (i % 7)] = 0;
  }
  // flat float4 staging: 64*41 = 2624 floats = 656 float4 (16B-aligned).
  {
    const long fbase = (long)b0 * 41;
    const int rows = (E - b0 < 64) ? (E - b0) : 64;
    const int flim = rows * 41;
    for (int i = tx; i < 656; i += 256) {
      const int q0 = i * 4;
      if (q0 >= flim) continue;
      if (q0 + 3 < flim) {
        const float4 v = *(const float4*)&eattr[fbase + q0];
        #pragma unroll
        for (int j = 0; j < 4; ++j) {
          const int q = q0 + j;
          const int row = q / 41;
          const int k = q - row * 41;
          As[row * 56 + k] = f2h(((const float*)&v)[j]);
        }
      } else {
        for (int q = q0; q < flim; ++q) {
          const int row = q / 41;
          const int k = q - row * 41;
          As[row * 56 + k] = f2h(eattr[fbase + q]);
        }
      }
    }
  }
  #pragma unroll
  for (int i = tx; i < 512; i += 256) WB[i] = WBe[i];
  __syncthreads();

  f32x4 acc0 = {0.f,0.f,0.f,0.f}, acc1 = {0.f,0.f,0.f,0.f};
  f32x4 acc2 = {0.f,0.f,0.f,0.f}, acc3 = {0.f,0.f,0.f,0.f};
  const int arow = 16 * w + (lane & 15);
  #pragma unroll
  for (int kstep = 0; kstep < 2; ++kstep) {
    const int koff = kstep * 32 + (lane >> 4) * 8;
    f16x8 a;
    if (koff < 48) {
      a = __builtin_bit_cast(f16x8, *(const uint4*)&As[arow * 56 + koff]);
    } else {
      const uint4 z = {0u, 0u, 0u, 0u};
      a = __builtin_bit_cast(f16x8, z);
    }
    const int bb = kstep * 256 + lane;
    const f16x8 b0v = __builtin_bit_cast(f16x8, WB[bb]);
    const f16x8 b1v = __builtin_bit_cast(f16x8, WB[bb + 64]);
    const f16x8 b2v = __builtin_bit_cast(f16x8, WB[bb + 128]);
    const f16x8 b3v = __builtin_bit_cast(f16x8, WB[bb + 192]);
    acc0 = __builtin_amdgcn_mfma_f32_16x16x32_f16(a, b0v, acc0, 0, 0, 0);
    acc1 = __builtin_amdgcn_mfma_f32_16x16x32_f16(a, b1v, acc1, 0, 0, 0);
    acc2 = __builtin_amdgcn_mfma_f32_16x16x32_f16(a, b2v, acc2, 0, 0, 0);
    acc3 = __builtin_amdgcn_mfma_f32_16x16x32_f16(a, b3v, acc3, 0, 0, 0);
  }
  __syncthreads();

  {
    const int rbase = 16 * w + (lane >> 4) * 4;
    const int cb = lane & 15;
    #pragma unroll
    for (int reg = 0; reg < 4; ++reg) {
      accs[(rbase + reg) * 68 + cb]      = acc0[reg];
      accs[(rbase + reg) * 68 + 16 + cb] = acc1[reg];
      accs[(rbase + reg) * 68 + 32 + cb] = acc2[reg];
      accs[(rbase + reg) * 68 + 48 + cb] = acc3[reg];
    }
  }
  __syncthreads();

  const int lr0 = ((tx >> 6) << 4) + (((tx >> 4) & 3) << 2);
  const int c0 = (tx & 15) << 2;
  const float4 bias = *(const float4*)&be[c0];
  #pragma unroll
  for (int ri = 0; ri < 4; ++ri) {
    const long e = b0 + lr0 + ri;
    if (e >= E) continue;
    float4 v = *(const float4*)&accs[(lr0 + ri) * 68 + c0];
    v.x += bias.x; v.y += bias.y; v.z += bias.z; v.w += bias.w;
    v.x = v.x >= 0.f ? v.x : 0.2f * v.x;  v.y = v.y >= 0.f ? v.y : 0.2f * v.y;
    v.z = v.z >= 0.f ? v.z : 0.2f * v.z;  v.w = v.w >= 0.f ? v.w : 0.2f * v.w;
    ushort4 u;
    u.x = f2h(v.x); u.y = f2h(v.y); u.z = f2h(v.z); u.w = f2h(v.w);
    *(ushort4*)&ea[(long)pos[e] * 64 + c0] = u;   // scattered posted store
  }
}

// ---------- fused E-GEMM via MFMA (r18/r22, unchanged) ----------------------
__global__ __launch_bounds__(256) void k_efused(
    const ushortt* __restrict__ ea, const uint4* __restrict__ WBg,
    ushortt* __restrict__ out, int E, const ushortt* __restrict__ P,
    const int* __restrict__ srcp, const int* __restrict__ dstp,
    const float* __restrict__ catt, float* __restrict__ a1,
    float* __restrict__ stats)
{
  __shared__ __align__(16) unsigned char smem[17408];
  __shared__ float atts[128];
  __shared__ float ssum[4], ssq[4];
  ushortt* As   = (ushortt*)smem;          // stride 72 halfs
  uint4*   WB   = (uint4*)(smem + 9216);
  float*   accs = (float*)smem;            // stride 68 floats (phase 2)

  const int tx = threadIdx.x;
  const int b0 = blockIdx.x * 64;
  const int lane = tx & 63;
  const int w = tx >> 6;

  if (tx < 128) atts[tx] = catt[tx];
  #pragma unroll
  for (int i = tx; i < 64 * 8; i += 256) {
    const int row = i >> 3;
    const int k8 = i & 7;
    long r = b0 + row; if (r >= E) r = E - 1;
    *(uint4*)&As[row * 72 + k8 * 8] = *(const uint4*)&ea[r * (long)64 + k8 * 8];
  }
  #pragma unroll
  for (int i = tx; i < 512; i += 256) WB[i] = WBg[i];
  __syncthreads();

  const int lr0 = ((tx >> 6) << 4) + (((tx >> 4) & 3) << 2);
  const int c0 = (tx & 15) << 2;
  ushort4 pdv[4], psv[4];
  #pragma unroll
  for (int ri = 0; ri < 4; ++ri) {
    long e = b0 + lr0 + ri; if (e >= E) e = E - 1;
    const int s = srcp[e];
    const int d = dstp[e];
    psv[ri] = *(const ushort4*)&P[(long)s * 64 + c0];
    pdv[ri] = *(const ushort4*)&P[(long)d * 64 + c0];
  }

  f32x4 acc0 = {0.f,0.f,0.f,0.f}, acc1 = {0.f,0.f,0.f,0.f};
  f32x4 acc2 = {0.f,0.f,0.f,0.f}, acc3 = {0.f,0.f,0.f,0.f};
  const int arow = 16 * w + (lane & 15);
  #pragma unroll
  for (int kstep = 0; kstep < 2; ++kstep) {
    const f16x8 a = __builtin_bit_cast(f16x8,
        *(const uint4*)&As[arow * 72 + kstep * 32 + (lane >> 4) * 8]);
    const int bb = kstep * 256 + lane;
    const f16x8 b0v = __builtin_bit_cast(f16x8, WB[bb]);
    const f16x8 b1v = __builtin_bit_cast(f16x8, WB[bb + 64]);
    const f16x8 b2v = __builtin_bit_cast(f16x8, WB[bb + 128]);
    const f16x8 b3v = __builtin_bit_cast(f16x8, WB[bb + 192]);
    acc0 = __builtin_amdgcn_mfma_f32_16x16x32_f16(a, b0v, acc0, 0, 0, 0);
    acc1 = __builtin_amdgcn_mfma_f32_16x16x32_f16(a, b1v, acc1, 0, 0, 0);
    acc2 = __builtin_amdgcn_mfma_f32_16x16x32_f16(a, b2v, acc2, 0, 0, 0);
    acc3 = __builtin_amdgcn_mfma_f32_16x16x32_f16(a, b3v, acc3, 0, 0, 0);
  }
  __syncthreads();

  {
    const int rbase = 16 * w + (lane >> 4) * 4;
    const int cb = lane & 15;
    #pragma unroll
    for (int reg = 0; reg < 4; ++reg) {
      accs[(rbase + reg) * 68 + cb]      = acc0[reg];
      accs[(rbase + reg) * 68 + 16 + cb] = acc1[reg];
      accs[(rbase + reg) * 68 + 32 + cb] = acc2[reg];
      accs[(rbase + reg) * 68 + 48 + cb] = acc3[reg];
    }
  }
  __syncthreads();

  float s1 = 0.f, s2 = 0.f;
  #pragma unroll
  for (int ri = 0; ri < 4; ++ri) {
    const long e = b0 + lr0 + ri;
    float part = 0.0f;
    if (e < E) {
      const float4 Pd = h4_to_f4(pdv[ri]);
      const float4 Ps = h4_to_f4(psv[ri]);
      const float4 m = *(const float4*)&accs[(lr0 + ri) * 68 + c0];
      float tj[4];
      const float ti0 = sp_f(Pd.x + m.x);
      const float ti1 = sp_f(Pd.y + m.y);
      const float ti2 = sp_f(Pd.z + m.z);
      const float ti3 = sp_f(Pd.w + m.w);
      tj[0] = sp_f(Ps.x + m.x);
      tj[1] = sp_f(Ps.y + m.y);
      tj[2] = sp_f(Ps.z + m.z);
      tj[3] = sp_f(Ps.w + m.w);
      ushort4 u;
      u.x = f2h(tj[0]); u.y = f2h(tj[1]); u.z = f2h(tj[2]); u.w = f2h(tj[3]);
      *(ushort4*)&out[e * 64 + c0] = u;
      part = ti0 * atts[c0] + ti1 * atts[c0 + 1] + ti2 * atts[c0 + 2] + ti3 * atts[c0 + 3]
           + tj[0] * atts[64 + c0] + tj[1] * atts[64 + c0 + 1]
           + tj[2] * atts[64 + c0 + 2] + tj[3] * atts[64 + c0 + 3];
    }
    #pragma unroll
    for (int off = 8; off; off >>= 1) part += __shfl_xor(part, off);
    if ((tx & 15) == 0 && e < E) {
      const float v = sp_f(part);
      a1[e] = v;
      s1 += v; s2 += v * v;
    }
  }
  s1 += __shfl_xor(s1, 16); s2 += __shfl_xor(s2, 16);
  s1 += __shfl_xor(s1, 32); s2 += __shfl_xor(s2, 32);
  if ((tx & 63) == 0) { ssum[tx >> 6] = s1; ssq[tx >> 6] = s2; }
  __syncthreads();
  if (tx == 0) {
    const int bk = blockIdx.x & 63;   // 64-way banked (r11/r15 lesson)
    atomicAdd(&stats[bk], ssum[0] + ssum[1] + ssum[2] + ssum[3]);
    atomicAdd(&stats[64 + bk], ssq[0] + ssq[1] + ssq[2] + ssq[3]);
  }
}

// ---------- CSR build (once per launch) -------------------------------------
__global__ __launch_bounds__(256) void k_count(
    const int* __restrict__ dst, int* __restrict__ counts, int E)
{
  for (int i = blockIdx.x * 256 + threadIdx.x; i < E; i += gridDim.x * 256)
    atomicAdd(&counts[dst[i]], 1);
}

__global__ __launch_bounds__(256) void k_scan1(
    const int* __restrict__ counts, int* __restrict__ offs,
    int* __restrict__ bsum, int N)
{
  __shared__ int sm[256];
  const int t = threadIdx.x;
  const int idx = blockIdx.x * 256 + t;
  const int v = (idx < N) ? counts[idx] : 0;
  sm[t] = v;
  __syncthreads();
  for (int off = 1; off < 256; off <<= 1) {
    const int u = (t >= off) ? sm[t - off] : 0;
    __syncthreads();
    sm[t] += u;
    __syncthreads();
  }
  if (idx < N) offs[idx] = sm[t] - v;
  if (t == 255) bsum[blockIdx.x] = sm[255];
}

__global__ __launch_bounds__(1024) void k_scan2(int* __restrict__ bsum, int SB)
{
  __shared__ int sm[1024];
  const int t = threadIdx.x;
  const int v = (t < SB) ? bsum[t] : 0;
  sm[t] = v;
  __syncthreads();
  for (int off = 1; off < 1024; off <<= 1) {
    const int u = (t >= off) ? sm[t - off] : 0;
    __syncthreads();
    sm[t] += u;
    __syncthreads();
  }
  if (t < SB) bsum[t] = sm[t] - v;
}

__global__ __launch_bounds__(256) void k_scan3(
    int* __restrict__ offs, const int* __restrict__ bsum, int N, int E)
{
  const int idx = blockIdx.x * 256 + threadIdx.x;
  if (idx < N) offs[idx] += bsum[blockIdx.x];
  if (idx == 0) offs[N] = E;
}

__global__ __launch_bounds__(256) void k_fill(
    const int* __restrict__ src, const int* __restrict__ dst,
    const int* __restrict__ offs, int* __restrict__ cursors,
    int* __restrict__ pos, int* __restrict__ srcp, int* __restrict__ dstp,
    int E)
{
  for (int i = blockIdx.x * 256 + threadIdx.x; i < E; i += gridDim.x * 256) {
    const int d = dst[i];
    const int p = offs[d] + atomicAdd(&cursors[d], 1);
    pos[i] = p;
    srcp[p] = src[i];
    dstp[p] = d;
  }
}

// ---------- aggregate: sequential CSR reads, banked stats -------------------
__global__ __launch_bounds__(256) void k_aggregate(
    const int* __restrict__ offs, const float* __restrict__ a1p,
    const ushortt* __restrict__ Mp, const float* __restrict__ stats,
    float invE, float* __restrict__ aggn, float* __restrict__ cs, int N)
{
  __shared__ float sm_mean, sm_scl;
  const int tx = threadIdx.x;
  if (tx < 64) {
    float s1 = stats[tx];
    float s2 = stats[64 + tx];
    #pragma unroll
    for (int off = 32; off; off >>= 1) {
      s1 += __shfl_xor(s1, off);
      s2 += __shfl_xor(s2, off);
    }
    if (tx == 0) {
      const float mean = s1 * invE;
      sm_mean = mean;
      sm_scl = rsqrtf(s2 * invE - mean * mean + 1e-5f);
    }
  }
  __syncthreads();
  const float mean = sm_mean;
  const float scl = sm_scl;

  const int t = tx & 63;
  const int wid = tx >> 6;
  float s = 0.f, s2 = 0.f;
  const long step = (long)gridDim.x * 4;
  for (long n = (long)blockIdx.x * 4 + wid; n < N; n += step) {
    const int o0 = offs[n];
    const int o1 = offs[n + 1];
    float av = 0.f, sew = 0.f;
    #pragma unroll 4
    for (int i = o0; i < o1; ++i) {
      const float w = __expf(sp_f((a1p[i] - mean) * scl));
      av = fmaf(h2f(Mp[(long)i * 64 + t]), w, av);
      sew += w;
    }
    const float v = (o1 > o0) ? av / sew : 0.0f;
    aggn[n * 64 + t] = v;
    s += v; s2 += v * v;
  }
  __shared__ float b1[256], b2[256];
  b1[tx] = s; b2[tx] = s2;
  __syncthreads();
  if (tx < 64) {
    const int bank = (blockIdx.x & 15) * 128;
    atomicAdd(&cs[bank + t], b1[t] + b1[64 + t] + b1[128 + t] + b1[192 + t]);
    atomicAdd(&cs[bank + 64 + t], b2[t] + b2[64 + t] + b2[128 + t] + b2[192 + t]);
  }
}

__global__ __launch_bounds__(256) void k_hnew(
    const float* __restrict__ aggn, const float* __restrict__ cs,
    float invN, float* __restrict__ h, int N)
{
  const int c = threadIdx.x & 63;
  const int r = threadIdx.x >> 6;
  float mn = 0.f, sq = 0.f;
  #pragma unroll
  for (int bk = 0; bk < 16; ++bk) {
    mn += cs[bk * 128 + c];
    sq += cs[bk * 128 + 64 + c];
  }
  mn *= invN; sq *= invN;
  const float scl = rsqrtf(sq - mn * mn + 1e-5f);
  for (long n = (long)blockIdx.x * 4 + r; n < N; n += (long)gridDim.x * 4)
    h[n * 64 + c] = sp_f((aggn[n * 64 + c] - mn) * scl);
}

// composition attention: per block 64-node tile, LDS-staged q + Wc, 8-way ILP
#define QSS 170
__global__ __launch_bounds__(256) void k_comp(
    const float* __restrict__ h, const float* __restrict__ gf,
    const int* __restrict__ batch, const float* __restrict__ Wc,
    const float* __restrict__ bc, const float* __restrict__ aw,
    const float* __restrict__ ab, float* __restrict__ aN, int N)
{
  __shared__ __align__(16) float qs[64 * QSS];
  __shared__ __align__(16) float Wcs[167 * 32];
  __shared__ float aws[32], bcs[32];
  const int tx = threadIdx.x;
  const int b0 = blockIdx.x * 64;
  for (int i = tx; i < 167 * 32; i += 256) Wcs[i] = Wc[i];
  if (tx < 32) { aws[tx] = aw[tx]; bcs[tx] = bc[tx]; }
  for (int i = tx; i < 64 * 16; i += 256) {
    const int n = i >> 4;
    const int c4 = (i & 15) << 2;
    long r = b0 + n; if (r >= N) r = N - 1;
    *(float4*)&qs[n * QSS + c4] = *(const float4*)&h[r * 64 + c4];
  }
  for (int i = tx; i < 64 * 103; i += 256) {
    const int n = i / 103;
    const int c = i % 103;
    long r = b0 + n; if (r >= N) r = N - 1;
    qs[n * QSS + 64 + c] = gf[(long)batch[r] * 103 + c];
  }
  __syncthreads();

  const int n = tx >> 2;
  const int colg = (tx & 3) << 3;
  float acc[8];
  #pragma unroll
  for (int j = 0; j < 8; ++j) acc[j] = 0.f;
  #pragma unroll 2
  for (int k = 0; k < 167; ++k) {
    const float q = qs[n * QSS + k];
    const float4 w0 = *(const float4*)&Wcs[k * 32 + colg];
    const float4 w1 = *(const float4*)&Wcs[k * 32 + colg + 4];
    acc[0] = fmaf(q, w0.x, acc[0]);
    acc[1] = fmaf(q, w0.y, acc[1]);
    acc[2] = fmaf(q, w0.z, acc[2]);
    acc[3] = fmaf(q, w0.w, acc[3]);
    acc[4] = fmaf(q, w1.x, acc[4]);
    acc[5] = fmaf(q, w1.y, acc[5]);
    acc[6] = fmaf(q, w1.z, acc[6]);
    acc[7] = fmaf(q, w1.w, acc[7]);
  }
  float val = 0.f;
  #pragma unroll
  for (int j = 0; j < 8; ++j)
    val += sp_f(acc[j] + bcs[colg + j]) * aws[colg + j];
  val += __shfl_xor(val, 1);
  val += __shfl_xor(val, 2);
  const long r = b0 + n;
  if ((tx & 3) == 0 && r < N) aN[r] = val + ab[0];
}

__global__ __launch_bounds__(64) void k_pool(
    const float* __restrict__ h, const float* __restrict__ aN,
    const int* __restrict__ batch, const float* __restrict__ fcW,
    const float* __restrict__ fcb, float* __restrict__ out, int N, int G)
{
  const int g = blockIdx.x;
  const int t = threadIdx.x;
  int lo = 0, hi = N;
  while (lo < hi) { int mid = (lo + hi) >> 1; if (batch[mid] < g) lo = mid + 1; else hi = mid; }
  const int s = lo;
  hi = N;
  while (lo < hi) { int mid = (lo + hi) >> 1; if (batch[mid] < g + 1) lo = mid + 1; else hi = mid; }
  const int e2 = lo;
  if (s >= e2) { if (t == 0) out[g] = fcb[0]; return; }
  float mx = -1e30f;
  for (int i = s + t; i < e2; i += 64) mx = fmaxf(mx, aN[i]);
  #pragma unroll
  for (int off = 32; off; off >>= 1) mx = fmaxf(mx, __shfl_xor(mx, off));
  float se = 0.f;
  for (int i = s + t; i < e2; i += 64) se += __expf(aN[i] - mx);
  #pragma unroll
  for (int off = 32; off; off >>= 1) se += __shfl_xor(se, off);
  float acc = 0.f;
  for (int n = s; n < e2; ++n) {
    const float w = __expf(aN[n] - mx);
    acc = fmaf(h[(long)n * 64 + t], w, acc);
  }
  float part = (acc / se) * fcW[t];
  #pragma unroll
  for (int off = 32; off; off >>= 1) part += __shfl_xor(part, off);
  if (t == 0) out[g] = part + fcb[0];
}

extern "C" void kernel_launch(void* const* d_in, const int* in_sizes, int n_in,
                              void* d_out, int out_size, void* d_ws, size_t ws_size,
                              hipStream_t stream)
{
  const float* x     = (const float*)d_in[0];
  const int*   eidx  = (const int*)  d_in[1];
  const float* eattr = (const float*)d_in[2];
  const int*   batch = (const int*)  d_in[3];
  const float* gfeat = (const float*)d_in[4];
  const float* embnW = (const float*)d_in[5];
  const float* embnb = (const float*)d_in[6];
  const float* embeW = (const float*)d_in[7];
  const float* embeb = (const float*)d_in[8];
  const float* convW = (const float*)d_in[9];
  const float* convA = (const float*)d_in[10];
  // d_in[11] = conv_bias: cancels exactly in training-mode BatchNorm
  const float* compW = (const float*)d_in[12];
  const float* compb = (const float*)d_in[13];
  const float* attW  = (const float*)d_in[14];
  const float* attb  = (const float*)d_in[15];
  const float* fcW   = (const float*)d_in[16];
  const float* fcb   = (const float*)d_in[17];
  float* out = (float*)d_out;

  const int N = in_sizes[0] / 92;
  const int E = in_sizes[1] / 2;
  const int G = in_sizes[4] / 103;
  const float invN = 1.0f / (float)N;
  const float invE = 1.0f / (float)E;

  // workspace (~140 MB)
  char* pw = (char*)d_ws;
  float* h     = (float*)pw;  pw += (size_t)N * 64 * 4;
  float* aggn  = (float*)pw;  pw += (size_t)N * 64 * 4;
  float* aE    = (float*)pw;  pw += (size_t)E * 4;        // a1 (CSR-ordered)
  float* statsB = (float*)pw; pw += 3 * SLOTS * 4;
  float* aN    = (float*)pw;  pw += (size_t)N * 4;
  int* counts  = (int*)pw;    pw += (size_t)N * 4;
  int* cursors = (int*)pw;    pw += (size_t)N * 4;
  int* offs    = (int*)pw;    pw += ((size_t)N + 1) * 4;
  int* bsum    = (int*)pw;    pw += 1024 * 4;
  int* pos     = (int*)pw;    pw += (size_t)E * 4;
  int* srcp    = (int*)pw;    pw += (size_t)E * 4;
  int* dstp    = (int*)pw;    pw += (size_t)E * 4;
  pw = (char*)(((size_t)pw + 63) & ~(size_t)63);
  uint4* WBg   = (uint4*)pw;   pw += 3 * 512 * 16;        // conv B frags
  uint4* WBe   = (uint4*)pw;   pw += 512 * 16;            // embed B frags
  ushortt* Pp  = (ushortt*)pw; pw += (size_t)N * 64 * 2;  // P fp16
  ushortt* ea  = (ushortt*)pw; pw += (size_t)E * 64 * 2;  // fp16, CSR-ordered
  ushortt* M   = (ushortt*)pw;                            // fp16 tj, CSR-ordered

  const int gE64 = (E + 63) / 64;
  const int gN64 = (N + 63) / 64;
  const int SB = (N + 255) / 256;

  hipMemsetAsync(counts, 0, 2 * (size_t)N * sizeof(int), stream);
  hipMemsetAsync(statsB, 0, 3 * SLOTS * sizeof(float), stream);
  k_count<<<2048, 256, 0, stream>>>(eidx + E, counts, E);
  k_scan1<<<SB, 256, 0, stream>>>(counts, offs, bsum, N);
  k_scan2<<<1, 1024, 0, stream>>>(bsum, SB);
  k_scan3<<<SB, 256, 0, stream>>>(offs, bsum, N, E);
  k_fill<<<2048, 256, 0, stream>>>(eidx, eidx + E, offs, cursors,
                                   pos, srcp, dstp, E);
  k_packW<<<3, 512, 0, stream>>>(convW, WBg);
  k_packWe<<<1, 512, 0, stream>>>(embeW, WBe);

  k_gemm_rt<92, 0, 1, 0, float, float><<<gN64, 256, 0, stream>>>(
      x, embnW, embnb, h, N, nullptr, 0.f);
  // ea-embed on the matrix pipe; output rows scattered to CSR slots (posted)
  k_embE<<<gE64, 256, 0, stream>>>(eattr, WBe, embeb, ea, E, pos);

  for (int l = 0; l < 3; ++l) {
    const float* Al = convA + (size_t)l * 128;
    float* statsL = statsB + (size_t)l * SLOTS;
    const float* Wl = convW + (size_t)l * 128 * 64;
    if (l == 0) {
      k_gemm_rt<64, 0, 0, 0, float, ushortt><<<gN64, 256, 0, stream>>>(
          h, Wl, nullptr, Pp, N, nullptr, 0.f);
    } else {
      k_gemm_rt<64, 0, 0, 1, float, ushortt><<<gN64, 256, 0, stream>>>(
          aggn, Wl, nullptr, Pp, N,
          statsB + (size_t)(l - 1) * SLOTS + 128, invN);
    }
    k_efused<<<gE64, 256, 0, stream>>>(ea, WBg + (size_t)l * 512, M, E,
                                       Pp, srcp, dstp, Al, aE, statsL);
    k_aggregate<<<2048, 256, 0, stream>>>(offs, aE, M, statsL,
                                          invE, aggn, statsL + 128, N);
  }

  k_hnew<<<2048, 256, 0, stream>>>(aggn, statsB + 2 * SLOTS + 128, invN, h, N);
  k_comp<<<gN64, 256, 0, stream>>>(h, gfeat, batch, compW, compb, attW, attb, aN, N);
  k_pool<<<G, 64, 0, stream>>>(h, aN, batch, fcW, fcb, out, N, G);

  (void)n_in; (void)out_size; (void)ws_size;
}